// Round 1
// baseline (1526.666 us; speedup 1.0000x reference)
//
#include <hip/hip_runtime.h>
#include <hip/hip_fp16.h>

// Problem constants
#define NN 100000
#define NE 1600000
#define DIN 32
#define DE 16
#define HC 64
#define NL 4
#define MHC 128
#define OUTC 10
#define NG 128

typedef _Float16 half2_t __attribute__((ext_vector_type(2)));

__device__ __forceinline__ float dot2f(unsigned pv, half2_t w2, float acc) {
#if __has_builtin(__builtin_amdgcn_fdot2)
  return __builtin_amdgcn_fdot2(__builtin_bit_cast(half2_t, pv), w2, acc, false);
#else
  __half2 h = *(__half2*)&pv; __half2 ww = *(__half2*)&w2;
  return acc + __low2float(h) * __low2float(ww) + __high2float(h) * __high2float(ww);
#endif
}

// ---- CSR build ----
__global__ __launch_bounds__(256) void k_deg(const int* __restrict__ dst, int* __restrict__ deg) {
  int e = blockIdx.x * 256 + threadIdx.x;
  if (e < NE) atomicAdd(&deg[dst[e]], 1);
}

__global__ __launch_bounds__(1024) void k_scan1(const int* __restrict__ deg, int* __restrict__ offs, int* __restrict__ bsum) {
  __shared__ int s[1024];
  int t = threadIdx.x;
  int i = blockIdx.x * 1024 + t;
  int v = (i < NN) ? deg[i] : 0;
  s[t] = v; __syncthreads();
  for (int d = 1; d < 1024; d <<= 1) {
    int x = 0;
    if (t >= d) x = s[t - d];
    __syncthreads();
    if (t >= d) s[t] += x;
    __syncthreads();
  }
  if (i < NN) offs[i] = s[t] - v;
  if (t == 1023) bsum[blockIdx.x] = s[t];
}

__global__ __launch_bounds__(128) void k_scan2(int* __restrict__ bsum, int nb) {
  __shared__ int s[128];
  int t = threadIdx.x;
  int v = (t < nb) ? bsum[t] : 0;
  s[t] = v; __syncthreads();
  for (int d = 1; d < 128; d <<= 1) {
    int x = 0;
    if (t >= d) x = s[t - d];
    __syncthreads();
    if (t >= d) s[t] += x;
    __syncthreads();
  }
  if (t < nb) bsum[t] = s[t] - v;
}

// also builds odeg = (start, deg) int2
__global__ __launch_bounds__(256) void k_scan3(int* __restrict__ offs, const int* __restrict__ bsum,
                                               const int* __restrict__ deg,
                                               int* __restrict__ cur, int2* __restrict__ odeg) {
  int i = blockIdx.x * 256 + threadIdx.x;
  if (i < NN) {
    int o = offs[i] + bsum[i >> 10];
    offs[i] = o;
    cur[i] = o;
    odeg[i] = make_int2(o, deg[i]);
  }
}

__global__ __launch_bounds__(256) void k_fill(const int* __restrict__ src, const int* __restrict__ dst,
                                              int* __restrict__ cur, int* __restrict__ csrc, int* __restrict__ ceid) {
  int e = blockIdx.x * 256 + threadIdx.x;
  if (e < NE) {
    int d = dst[e];
    int pos = atomicAdd(&cur[d], 1);
    csrc[pos] = src[e];
    ceid[pos] = e;
  }
}

// ---- gather-cast: eattr (f32, original order) -> e16 (f16-packed, CSR order) ----
__global__ __launch_bounds__(256) void k_cast(const int* __restrict__ ceid,
                                              const float4* __restrict__ eattr4,
                                              uint4* __restrict__ e16) {
  int p = blockIdx.x * 256 + threadIdx.x;
  if (p >= NE) return;
  int e = ceid[p];
  float4 a0 = eattr4[(size_t)e * 4 + 0];
  float4 a1 = eattr4[(size_t)e * 4 + 1];
  float4 a2 = eattr4[(size_t)e * 4 + 2];
  float4 a3 = eattr4[(size_t)e * 4 + 3];
  __half2 h0 = __floats2half2_rn(a0.x, a0.y), h1 = __floats2half2_rn(a0.z, a0.w);
  __half2 h2 = __floats2half2_rn(a1.x, a1.y), h3 = __floats2half2_rn(a1.z, a1.w);
  __half2 h4 = __floats2half2_rn(a2.x, a2.y), h5 = __floats2half2_rn(a2.z, a2.w);
  __half2 h6 = __floats2half2_rn(a3.x, a3.y), h7 = __floats2half2_rn(a3.z, a3.w);
  uint4 o0 = make_uint4(*(unsigned*)&h0, *(unsigned*)&h1, *(unsigned*)&h2, *(unsigned*)&h3);
  uint4 o1 = make_uint4(*(unsigned*)&h4, *(unsigned*)&h5, *(unsigned*)&h6, *(unsigned*)&h7);
  e16[(size_t)p * 2 + 0] = o0;
  e16[(size_t)p * 2 + 1] = o1;
}

// ---- edge weights -> f16 pairs [4 layers][64 ch][8 dwords] + padded biases [4][64] ----
__global__ __launch_bounds__(256) void k_wprep(const float* __restrict__ l0ew, const float* __restrict__ l0eb,
                                               const float* __restrict__ ew, const float* __restrict__ eb,
                                               unsigned* __restrict__ ewh, float* __restrict__ ebp) {
  int i = blockIdx.x * 256 + threadIdx.x;
  if (i < 2048) {
    int L = i >> 9, r = i & 511;
    int c = r >> 3, t = r & 7;
    float a, b;
    if (L == 0) {
      a = (c < 32) ? l0ew[c * 16 + 2 * t] : 0.f;
      b = (c < 32) ? l0ew[c * 16 + 2 * t + 1] : 0.f;
    } else {
      a = ew[(size_t)(L - 1) * 1024 + c * 16 + 2 * t];
      b = ew[(size_t)(L - 1) * 1024 + c * 16 + 2 * t + 1];
    }
    __half2 h = __floats2half2_rn(a, b);
    ewh[i] = *(unsigned*)&h;
  }
  if (i < 256) {
    int L = i >> 6, c = i & 63;
    ebp[i] = (L == 0) ? ((c < 32) ? l0eb[c] : 0.f) : eb[(size_t)(L - 1) * 64 + c];
  }
}

// ---- graph boundaries (batch sorted) ----
__global__ __launch_bounds__(256) void k_gstart(const int* __restrict__ batch, int* __restrict__ gstart) {
  int i = blockIdx.x * 256 + threadIdx.x;
  if (i >= NN) return;
  int b = batch[i];
  int bp = (i == 0) ? -1 : batch[i - 1];
  for (int g = bp + 1; g <= b; g++) gstart[g] = i;
  if (i == NN - 1)
    for (int g = b + 1; g <= NG; g++) gstart[g] = NN;
}

// ---- w2 transpose ----
__global__ __launch_bounds__(256) void k_tr(const float* __restrict__ l0w2, const float* __restrict__ w2,
                                            float* __restrict__ w2t) {
  int id = blockIdx.x * 256 + threadIdx.x;
  int mat = id >> 12;
  int j = id & 4095;
  int c1 = j >> 6, c2 = j & 63;
  const float* s = (mat == 0) ? l0w2 : (w2 + (size_t)(mat - 1) * 4096);
  w2t[mat * 4096 + j] = s[c2 * 64 + c1];
}

__global__ __launch_bounds__(256) void k_xpad(const float* __restrict__ x, float* __restrict__ xpad) {
  int i = blockIdx.x * 256 + threadIdx.x;   // over NN*64
  if (i >= NN * 64) return;
  int cc = i & 63;
  xpad[i] = (cc < 32) ? x[(size_t)(i >> 6) * 32 + cc] : 0.f;
}

// ---- edge aggregation: wave per node, lane = channel; CSR-ordered f16 eattr via
//      coalesced block load (8 edges/load) + readlane pairs + fdot2.
//      16 x-gathers prefetched per chunk. Optional fused BN+relu on gathered x. ----
template<bool BN>
__global__ __launch_bounds__(256) void k_edgeH(
    const int* __restrict__ csrc, const int2* __restrict__ odeg,
    const float* __restrict__ xsrc, const float* __restrict__ scp, const float* __restrict__ shp,
    const unsigned* __restrict__ e16,
    const unsigned* __restrict__ ewh, const float* __restrict__ ebf,
    float* __restrict__ hpre)
{
  int gt = blockIdx.x * 256 + threadIdx.x;
  int node = gt >> 6;
  if (node >= NN) return;
  int c = threadIdx.x & 63;
  half2_t wh[8];
  {
    const uint4* wv = (const uint4*)(ewh + (size_t)c * 8);
    uint4 q0 = wv[0], q1 = wv[1];
    wh[0] = __builtin_bit_cast(half2_t, q0.x); wh[1] = __builtin_bit_cast(half2_t, q0.y);
    wh[2] = __builtin_bit_cast(half2_t, q0.z); wh[3] = __builtin_bit_cast(half2_t, q0.w);
    wh[4] = __builtin_bit_cast(half2_t, q1.x); wh[5] = __builtin_bit_cast(half2_t, q1.y);
    wh[6] = __builtin_bit_cast(half2_t, q1.z); wh[7] = __builtin_bit_cast(half2_t, q1.w);
  }
  float bcv = ebf[c];
  float scv = 1.f, shv = 0.f;
  if (BN) { scv = scp[c]; shv = shp[c]; }
  int2 od = odeg[node];
  int start = od.x, n = od.y;
  float acc = 0.f;

  for (int base = 0; base < n; base += 16) {
    int cn = min(16, n - base);
    // src indices for the chunk (lanes 0..cn-1)
    int sidx = 0;
    if (c < cn) sidx = csrc[start + base + c];
    // coalesced f16 eattr block loads: one load = 8 edges (64 dwords); lane c holds dword c
    unsigned ead0 = e16[(size_t)(start + base) * 8 + c];
    unsigned ead1 = 0;
    if (cn > 8) ead1 = e16[(size_t)(start + base + 8) * 8 + c];
    // prefetch all x-gathers for the chunk
    float xv[16];
    #pragma unroll
    for (int u = 0; u < 16; u++) {
      if (u < cn) {
        int s = __shfl(sidx, u);
        xv[u] = xsrc[(size_t)s * 64 + c];
      } else xv[u] = 0.f;
    }
    #pragma unroll
    for (int u = 0; u < 16; u++) {
      if (u >= cn) break;
      unsigned eb_ = (u < 8) ? ead0 : ead1;
      int u2 = u & 7;
      float el = bcv;
      #pragma unroll
      for (int t = 0; t < 8; t++) {
        unsigned pv = (unsigned)__builtin_amdgcn_readlane((int)eb_, u2 * 8 + t);
        el = dot2f(pv, wh[t], el);
      }
      float xs = xv[u];
      if (BN) xs = fmaxf(fmaf(xs, scv, shv), 0.f);
      acc += fmaxf(xs + el, 0.f);
    }
  }

  float xself = xsrc[(size_t)node * 64 + c];
  if (BN) xself = fmaxf(fmaf(xself, scv, shv), 0.f);
  hpre[(size_t)node * 64 + c] = xself + acc;
}

// ---- fused node MLP + BN-stats epilogue; input rows have stride 64.
//      Restructured vs v1: per-thread mid activations 'a' live in a padded private
//      LDS row (not registers), second GEMM chunked 16-wide -> peak live regs
//      ~CIN+16+addr, no scratch spill. Block=128 threads (1 row/thread). ----
template<int CIN>
__global__ __launch_bounds__(128) void k_mlp(
    const float* __restrict__ hpre,
    const float* __restrict__ w1f, const float* __restrict__ b1f,
    const float* __restrict__ w2tf, const float* __restrict__ b2v,
    float* __restrict__ h2, float* __restrict__ bnsq)
{
  __shared__ float a_lds[128 * 65];   // [thread][mid-channel], pad 65 -> bank (t+c)%32, 2-way = free
  __shared__ float part[2][128];
  int row0 = blockIdx.x * 128 + threadIdx.x;
  bool act = row0 < NN;
  int row = act ? row0 : (NN - 1);
  float hrow[CIN];
  const float4* hp = (const float4*)(hpre + (size_t)row * 64);
  #pragma unroll
  for (int k = 0; k < CIN / 4; k++) {
    float4 v = hp[k];
    hrow[4*k] = v.x; hrow[4*k+1] = v.y; hrow[4*k+2] = v.z; hrow[4*k+3] = v.w;
  }
  float* arow = a_lds + threadIdx.x * 65;
  // stage 1: a[c1] = relu(b1 + w1[c1,:] . hrow)  -> private LDS row
  #pragma unroll 4
  for (int c1 = 0; c1 < 64; c1++) {
    float a = b1f[c1];
    #pragma unroll
    for (int k = 0; k < CIN; k++) a = fmaf(w1f[c1 * CIN + k], hrow[k], a);
    arow[c1] = fmaxf(a, 0.f);
  }
  // stage 2: 4 chunks of 16 output channels; acc in registers only
  int wid = threadIdx.x >> 6, lane = threadIdx.x & 63;
  float4* out = (float4*)(h2 + (size_t)row * 64);
  #pragma unroll
  for (int ch = 0; ch < 4; ch++) {
    float acc[16];
    #pragma unroll
    for (int j = 0; j < 16; j++) acc[j] = b2v[ch * 16 + j];
    #pragma unroll 4
    for (int c1 = 0; c1 < 64; c1++) {
      float av = arow[c1];
      #pragma unroll
      for (int j = 0; j < 16; j++) acc[j] = fmaf(w2tf[c1 * 64 + ch * 16 + j], av, acc[j]);
    }
    #pragma unroll
    for (int j = 0; j < 16; j++) acc[j] = act ? fmaxf(acc[j], 0.f) : 0.f;
    if (act) {
      #pragma unroll
      for (int q = 0; q < 4; q++)
        out[ch * 4 + q] = make_float4(acc[4*q], acc[4*q+1], acc[4*q+2], acc[4*q+3]);
    }
    // BN partial stats for these 16 channels
    #pragma unroll
    for (int j = 0; j < 16; j++) {
      float s = acc[j], q = s * s;
      #pragma unroll
      for (int m = 1; m < 64; m <<= 1) { s += __shfl_xor(s, m); q += __shfl_xor(q, m); }
      if (lane == 0) { int cc = ch * 16 + j; part[wid][cc] = s; part[wid][64 + cc] = q; }
    }
  }
  __syncthreads();
  if (threadIdx.x < 128) {
    float v = part[0][threadIdx.x] + part[1][threadIdx.x];
    atomicAdd(&bnsq[threadIdx.x], v);
  }
}

__global__ __launch_bounds__(64) void k_bnfin(const float* __restrict__ bnsq,
                                              const float* __restrict__ gamma, const float* __restrict__ beta,
                                              int layer, float* __restrict__ scs, float* __restrict__ shs) {
  int c = threadIdx.x;
  if (c >= 64) return;
  const float* sl = bnsq + layer * 128;
  float mu = sl[c] * (1.0f / NN);
  float var = sl[64 + c] * (1.0f / NN) - mu * mu;
  float r = rsqrtf(var + 1e-5f);
  float s = gamma[layer * 64 + c] * r;
  scs[layer * 64 + c] = s;
  shs[layer * 64 + c] = beta[layer * 64 + c] - mu * s;
}

// ---- pool: BN+relu on the fly; batch sorted -> contiguous ranges ----
__global__ __launch_bounds__(256) void k_pool2(const float* __restrict__ h2, const float* __restrict__ sc,
                                               const float* __restrict__ sh, const int* __restrict__ gstart,
                                               float* __restrict__ pooled) {
  int g = blockIdx.x >> 2, sub = blockIdx.x & 3;
  int s = gstart[g], e = gstart[g + 1];
  int c = threadIdx.x & 63, rg = threadIdx.x >> 6;
  float scv = sc[c], shv = sh[c];
  float acc = 0.f;
  for (int r = s + sub * 4 + rg; r < e; r += 16)
    acc += fmaxf(fmaf(h2[(size_t)r * 64 + c], scv, shv), 0.f);
  __shared__ float ls[256];
  ls[threadIdx.x] = acc;
  __syncthreads();
  if (rg == 0) {
    float v = ls[c] + ls[64 + c] + ls[128 + c] + ls[192 + c];
    atomicAdd(&pooled[g * 64 + c], v);
  }
}

__global__ __launch_bounds__(128) void k_head(const float* __restrict__ pooled, const int* __restrict__ gstart,
                                              const float* __restrict__ hw1, const float* __restrict__ hb1,
                                              const float* __restrict__ hw2, const float* __restrict__ hb2,
                                              float* __restrict__ out) {
  __shared__ float p[64];
  __shared__ float z[128];
  int g = blockIdx.x, t = threadIdx.x;
  if (t < 64) {
    int cn = gstart[g + 1] - gstart[g];
    float inv = 1.0f / (float)(cn > 0 ? cn : 1);
    p[t] = pooled[g * 64 + t] * inv;
  }
  __syncthreads();
  float a = hb1[t];
  #pragma unroll
  for (int k = 0; k < 64; k++) a = fmaf(hw1[t * 64 + k], p[k], a);
  z[t] = fmaxf(a, 0.f);
  __syncthreads();
  if (t < OUTC) {
    float b = hb2[t];
    #pragma unroll
    for (int k = 0; k < 128; k++) b = fmaf(hw2[t * 128 + k], z[k], b);
    out[g * OUTC + t] = b;
  }
}

extern "C" void kernel_launch(void* const* d_in, const int* in_sizes, int n_in,
                              void* d_out, int out_size, void* d_ws, size_t ws_size,
                              hipStream_t stream) {
  const float* x_f   = (const float*)d_in[0];
  const int*   ei    = (const int*)d_in[1];
  const float* eattr = (const float*)d_in[2];
  const int*   batch = (const int*)d_in[3];
  const float* l0_ew = (const float*)d_in[4];
  const float* l0_eb = (const float*)d_in[5];
  const float* l0_w1 = (const float*)d_in[6];
  const float* l0_b1 = (const float*)d_in[7];
  const float* l0_w2 = (const float*)d_in[8];
  const float* l0_b2 = (const float*)d_in[9];
  const float* ew    = (const float*)d_in[10];
  const float* eb    = (const float*)d_in[11];
  const float* w1    = (const float*)d_in[12];
  const float* b1    = (const float*)d_in[13];
  const float* w2    = (const float*)d_in[14];
  const float* b2    = (const float*)d_in[15];
  const float* bng   = (const float*)d_in[16];
  const float* bnb   = (const float*)d_in[17];
  const float* hw1   = (const float*)d_in[18];
  const float* hb1   = (const float*)d_in[19];
  const float* hw2   = (const float*)d_in[20];
  const float* hb2   = (const float*)d_in[21];
  const int* esrc = ei;
  const int* edst = ei + NE;

  char* wsb = (char*)d_ws;
  size_t off = 0;
  auto A = [&](size_t bytes) -> void* {
    void* p = wsb + off;
    off = (off + bytes + 255) & ~(size_t)255;
    return p;
  };
  int*   csrc = (int*)A((size_t)NE * 4);
  int*   ceid = (int*)A((size_t)NE * 4);
  int*   offs = (int*)A((size_t)NN * 4);
  int*   deg  = (int*)A((size_t)NN * 4);
  int*   cur  = (int*)A((size_t)NN * 4);
  int2*  odeg = (int2*)A((size_t)NN * 8);
  int*   bsum = (int*)A(128 * 4);
  int*   gst  = (int*)A((NG + 1) * 4);
  float* xpad = (float*)A((size_t)NN * 64 * 4);
  float* hpre = (float*)A((size_t)NN * 64 * 4);
  float* h2   = (float*)A((size_t)NN * 64 * 4);
  float* bnsq = (float*)A(4 * 128 * 4);   // [layer][sum64|sq64]
  float* scs  = (float*)A(4 * 64 * 4);
  float* shs  = (float*)A(4 * 64 * 4);
  float* pooled = (float*)A((size_t)NG * 64 * 4);
  float* w2t  = (float*)A(4 * 4096 * 4);
  unsigned* ewh = (unsigned*)A(2048 * 4);   // f16-pair edge weights, 4 layers
  float* ebp  = (float*)A(256 * 4);         // padded edge biases, 4 layers
  unsigned* e16 = (unsigned*)A(((size_t)NE + 16) * 32);  // f16 eattr, CSR order, 8 dwords/edge

  hipMemsetAsync(deg, 0, (size_t)NN * 4, stream);
  hipMemsetAsync(bnsq, 0, 4 * 128 * 4, stream);
  hipMemsetAsync(pooled, 0, (size_t)NG * 64 * 4, stream);

  k_tr<<<64, 256, 0, stream>>>(l0_w2, w2, w2t);
  k_wprep<<<8, 256, 0, stream>>>(l0_ew, l0_eb, ew, eb, ewh, ebp);
  k_xpad<<<(NN * 64 + 255) / 256, 256, 0, stream>>>(x_f, xpad);
  k_gstart<<<(NN + 255) / 256, 256, 0, stream>>>(batch, gst);

  k_deg<<<(NE + 255) / 256, 256, 0, stream>>>(edst, deg);
  k_scan1<<<98, 1024, 0, stream>>>(deg, offs, bsum);
  k_scan2<<<1, 128, 0, stream>>>(bsum, 98);
  k_scan3<<<(NN + 255) / 256, 256, 0, stream>>>(offs, bsum, deg, cur, odeg);
  k_fill<<<(NE + 255) / 256, 256, 0, stream>>>(esrc, edst, cur, csrc, ceid);
  k_cast<<<(NE + 255) / 256, 256, 0, stream>>>(ceid, (const float4*)eattr, (uint4*)e16);

  const int nodeBlocks = (NN * 64 + 255) / 256;
  const int rowBlocks = (NN + 127) / 128;

  // ---- layer 0 (padded to C=64; BN=false) ----
  k_edgeH<false><<<nodeBlocks, 256, 0, stream>>>(csrc, odeg, xpad, nullptr, nullptr,
                                                 e16, ewh, ebp, hpre);
  k_mlp<32><<<rowBlocks, 128, 0, stream>>>(hpre, l0_w1, l0_b1, w2t, l0_b2, h2, bnsq + 0);
  k_bnfin<<<1, 64, 0, stream>>>(bnsq, bng, bnb, 0, scs, shs);

  // ---- layers 1..3: gather from h2 with fused BN(prev)+relu ----
  for (int i = 0; i < 3; i++) {
    k_edgeH<true><<<nodeBlocks, 256, 0, stream>>>(csrc, odeg, h2,
                                                  scs + i * 64, shs + i * 64,
                                                  e16, ewh + (size_t)(i + 1) * 512, ebp + (i + 1) * 64, hpre);
    k_mlp<64><<<rowBlocks, 128, 0, stream>>>(hpre, w1 + (size_t)i * 4096, b1 + (size_t)i * 64,
                                             w2t + (size_t)(i + 1) * 4096, b2 + (size_t)i * 64,
                                             h2, bnsq + (i + 1) * 128);
    k_bnfin<<<1, 64, 0, stream>>>(bnsq, bng, bnb, i + 1, scs, shs);
  }

  // ---- pool (applies BN layer 3) + head ----
  k_pool2<<<NG * 4, 256, 0, stream>>>(h2, scs + 3 * 64, shs + 3 * 64, gst, pooled);
  k_head<<<NG, 128, 0, stream>>>(pooled, gst, hw1, hb1, hw2, hb2, (float*)d_out);
}